// Round 8
// baseline (224.587 us; speedup 1.0000x reference)
//
#include <hip/hip_runtime.h>
#include <math.h>

// Problem constants
#define B_   64
#define N_   197
#define C_   768
#define H_   12
#define HD_  64
#define BH_  (B_ * H_)          // 768
#define M_   (B_ * N_)          // 12608

typedef _Float16 half8 __attribute__((ext_vector_type(8)));
typedef _Float16 half4 __attribute__((ext_vector_type(4)));
typedef float    f32x4 __attribute__((ext_vector_type(4)));

// Workspace byte offsets (all 16B aligned)
#define XH_OFF   0u           // 12608*768 fp16      = 19,365,888 B
#define WQH_OFF  19365888u    // 2304*768 fp16       =  3,538,944 B
#define WPH_OFF  22904832u    // 768*768 fp16        =  1,179,648 B
#define QH_OFF   24084480u    // [bh][197][64] fp16  = 19,365,888 B
#define KH_OFF   43450368u    // [bh][197][64] fp16
#define VH_OFF   62816256u    // [bh][197][64] fp16
#define OH_OFF   82182144u    // [B][N][C] fp16      = 19,365,888 B
#define P0_OFF   101548032u   // [bh][196] fp32      =    602,112 B
#define WS_BYTES 102150144u

__device__ __forceinline__ half8 h8zero() {
    half8 z;
    #pragma unroll
    for (int i = 0; i < 8; ++i) z[i] = (_Float16)0;
    return z;
}

// async 16B global -> LDS (wave-uniform LDS base + lane*16; per-lane global addr)
__device__ __forceinline__ void async16(const _Float16* g, _Float16* l) {
    __builtin_amdgcn_global_load_lds(
        (const __attribute__((address_space(1))) void*)g,
        (__attribute__((address_space(3))) void*)l,
        16, 0, 0);
}

// m204 bijective XCD-chunk swizzle
__device__ __forceinline__ int xcd_swz(int i, int nwg) {
    const int q = nwg >> 3, r = nwg & 7;
    const int xcd = i & 7, j = i >> 3;
    return (xcd < r ? xcd * (q + 1) : r * (q + 1) + (xcd - r) * q) + j;
}

// ---------------------------------------------------------------------------
__global__ void k_ws_too_small(float* out, float ws_bytes) { out[0] = -ws_bytes; }

// ---------------------------------------------------------------------------
// fp32 -> fp16 bulk convert, all three tensors in one launch.
__global__ __launch_bounds__(256) void k_cvt_all(const float* __restrict__ x,
                                                 const float* __restrict__ wq,
                                                 const float* __restrict__ wp,
                                                 _Float16* __restrict__ Xh,
                                                 _Float16* __restrict__ Wqh,
                                                 _Float16* __restrict__ Wph) {
    int i = blockIdx.x * blockDim.x + threadIdx.x;
    const float* src;
    _Float16*    dst;
    if (i < 1210368)      { src = x;  dst = Xh; }
    else if (i < 1431552) { src = wq; dst = Wqh; i -= 1210368; }
    else                  { src = wp; dst = Wph; i -= 1431552; }
    float4 f0 = *(const float4*)(src + (size_t)i * 8);
    float4 f1 = *(const float4*)(src + (size_t)i * 8 + 4);
    half8 h;
    h[0]=(_Float16)f0.x; h[1]=(_Float16)f0.y; h[2]=(_Float16)f0.z; h[3]=(_Float16)f0.w;
    h[4]=(_Float16)f1.x; h[5]=(_Float16)f1.y; h[6]=(_Float16)f1.z; h[7]=(_Float16)f1.w;
    *(half8*)(dst + (size_t)i * 8) = h;
}

// ---------------------------------------------------------------------------
// 256x256 NT-GEMM core (qkv): 8 waves (2Mx4N, per-wave 128x64), BK=32,
// 3-buffer LDS ring, prefetch distance 2 K-tiles (m201-style depth), one
// vmcnt(8) + 2 barriers per K-tile. LDS 96 KiB linear dest for DMA; T2 swizzle
// via pre-permuted global source chunk (c8 ^ ((row>>1)&3)) + matching read
// chunk (kq ^ ((ln>>1)&3))  [both-sides rule #21; <=2-way banks].
__device__ __forceinline__ void mfma_nt_core_256(const _Float16* __restrict__ A,
                                                 const _Float16* __restrict__ B,
                                                 int M, int K, int m0, int n0,
                                                 _Float16* As, _Float16* Bs,
                                                 f32x4 (&acc)[8][4]) {
    const int tid  = threadIdx.x;
    const int lane = tid & 63;
    const int w    = tid >> 6;
    const int wm   = w >> 2, wn = w & 3;
    const int ln   = lane & 15, kq = lane >> 4;

    // staging: call l covers rows l*128 + (tid>>2); chunk c8 = tid&3.
    // source col pre-permuted: (c8 ^ ((row>>1)&3))<<3 = ((tid&3)^((tid>>3)&3))<<3
    // (row+128 keeps the same permute: 128>>1 = 64 == 0 mod 4)
    const int srow = tid >> 2;                               // 0..127
    const int kcs  = (((tid & 3) ^ ((tid >> 3) & 3)) << 3);  // src col (halves)
    int ra0 = m0 +       srow; if (ra0 >= M) ra0 = 0;        // clamp; garbage
    int ra1 = m0 + 128 + srow; if (ra1 >= M) ra1 = 0;        // dropped in epilogue
    const _Float16* A0 = A + (size_t)ra0 * K + kcs;
    const _Float16* A1 = A + (size_t)ra1 * K + kcs;
    const _Float16* B0 = B + (size_t)(n0 +       srow) * K + kcs;
    const _Float16* B1 = B + (size_t)(n0 + 128 + srow) * K + kcs;
    const int dOff = w << 9;      // wave-uniform dest base (halves) within a call

    // read addressing (A-frag: lane holds A[m=ln][k=kq*8+j])
    const int rdx   = ((kq ^ ((ln >> 1) & 3)) << 3);   // swizzled k-chunk (halves)
    const int aBase = wm * 4096 + ln * 32;
    const int bBase = wn * 2048 + ln * 32;

    // prologue: prime K-tiles 0,1,2 into bufs 0,1,2 (4 calls each)
    #pragma unroll
    for (int p = 0; p < 3; ++p) {
        const int koff = p << 5;
        _Float16* dA = As + p * 8192 + dOff;
        _Float16* dB = Bs + p * 8192 + dOff;
        async16(A0 + koff, dA);   async16(A1 + koff, dA + 4096);
        async16(B0 + koff, dB);   async16(B1 + koff, dB + 4096);
    }

    const int NT = K >> 5;        // 24
    int cur = 0;
    #pragma unroll 1
    for (int t = 0; t < NT; ++t) {
        // wait: own 4 loads of tile t done; up to 8 (t+1,t+2) stay in flight
        if (t < NT - 2)       asm volatile("s_waitcnt vmcnt(8)" ::: "memory");
        else if (t == NT - 2) asm volatile("s_waitcnt vmcnt(4)" ::: "memory");
        else                  asm volatile("s_waitcnt vmcnt(0)" ::: "memory");
        __builtin_amdgcn_s_barrier();            // all waves' DMA for t landed
        __builtin_amdgcn_sched_barrier(0);

        const _Float16* Ac = As + cur * 8192;
        const _Float16* Bc = Bs + cur * 8192;
        half8 af[8], bf[4];
        #pragma unroll
        for (int m4 = 0; m4 < 8; ++m4)
            af[m4] = *(const half8*)&Ac[aBase + m4 * 512 + rdx];
        #pragma unroll
        for (int n2 = 0; n2 < 4; ++n2)
            bf[n2] = *(const half8*)&Bc[bBase + n2 * 512 + rdx];
        #pragma unroll
        for (int m4 = 0; m4 < 8; ++m4)
            #pragma unroll
            for (int n2 = 0; n2 < 4; ++n2)
                acc[m4][n2] = __builtin_amdgcn_mfma_f32_16x16x32_f16(af[m4], bf[n2], acc[m4][n2], 0, 0, 0);

        asm volatile("s_waitcnt lgkmcnt(0)" ::: "memory");
        __builtin_amdgcn_sched_barrier(0);
        __builtin_amdgcn_s_barrier();            // all reads of buf cur done

        if (t + 3 < NT) {                        // refill cur with tile t+3
            const int koff = (t + 3) << 5;
            _Float16* dA = As + cur * 8192 + dOff;
            _Float16* dB = Bs + cur * 8192 + dOff;
            async16(A0 + koff, dA);   async16(A1 + koff, dA + 4096);
            async16(B0 + koff, dB);   async16(B1 + koff, dB + 4096);
        }
        cur = (cur == 2) ? 0 : cur + 1;
    }
}

// ---------------------------------------------------------------------------
// 128x128 NT-GEMM core (proj): 4 waves, 2-phase dbuf global_load_lds.
__device__ __forceinline__ void mfma_nt_core_h(const _Float16* __restrict__ A,
                                               const _Float16* __restrict__ B,
                                               int M, int K, int m0, int n0,
                                               _Float16* As, _Float16* Bs,
                                               f32x4 (&acc)[4][4]) {
    const int tid  = threadIdx.x;
    const int wave = tid >> 6, lane = tid & 63;
    const int wr   = (wave >> 1) << 6;
    const int wc   = (wave & 1) << 6;
    const int ln   = lane & 15, kq = lane >> 4;

    const int row0 = tid >> 2;
    const int ch0  = (tid & 3) << 3;
    int ar0 = m0 + row0;        if (ar0 >= M) ar0 = 0;
    int ar1 = m0 + 64 + row0;   if (ar1 >= M) ar1 = 0;
    const _Float16* A0 = A + (size_t)ar0 * K + ch0;
    const _Float16* A1 = A + (size_t)ar1 * K + ch0;
    const _Float16* B0 = B + (size_t)(n0 + row0) * K + ch0;
    const _Float16* B1 = B + (size_t)(n0 + 64 + row0) * K + ch0;
    _Float16* AsD = As + (wave << 9);
    _Float16* BsD = Bs + (wave << 9);

    async16(A0, AsD);        async16(A1, AsD + 2048);
    async16(B0, BsD);        async16(B1, BsD + 2048);
    __syncthreads();

    int cur = 0;
    for (int k0 = 0; k0 < K; k0 += 32) {
        const int nxt = cur ^ 1;
        if (k0 + 32 < K) {
            const int nb = nxt << 12;
            async16(A0 + k0 + 32, AsD + nb);
            async16(A1 + k0 + 32, AsD + nb + 2048);
            async16(B0 + k0 + 32, BsD + nb);
            async16(B1 + k0 + 32, BsD + nb + 2048);
        }
        const _Float16* Ac = As + (cur << 12);
        const _Float16* Bc = Bs + (cur << 12);
        half8 af[4], bf[4];
        #pragma unroll
        for (int t = 0; t < 4; ++t) {
            af[t] = *(const half8*)&Ac[(wr + t * 16 + ln) * 32 + kq * 8];
            bf[t] = *(const half8*)&Bc[(wc + t * 16 + ln) * 32 + kq * 8];
        }
        #pragma unroll
        for (int i = 0; i < 4; ++i)
            #pragma unroll
            for (int j = 0; j < 4; ++j)
                acc[i][j] = __builtin_amdgcn_mfma_f32_16x16x32_f16(af[i], bf[j], acc[i][j], 0, 0, 0);
        __syncthreads();
        cur = nxt;
    }
}

// ---------------------------------------------------------------------------
// qkv = x @ w_qkv^T (256^2 BK32 deep-prefetch core); scatter -> Qh/Kh/Vh fp16
__global__ __launch_bounds__(512, 2) void k_qkv_mfma(const _Float16* __restrict__ Xh,
                                                     const _Float16* __restrict__ Wq,
                                                     _Float16* __restrict__ Qh,
                                                     _Float16* __restrict__ Kh,
                                                     _Float16* __restrict__ Vh) {
    __shared__ _Float16 As[24576];
    __shared__ _Float16 Bs[24576];
    const int work = xcd_swz(blockIdx.x, 50 * 9);
    const int m0 = (work / 9) << 8;
    const int n0 = (work % 9) << 8;
    f32x4 acc[8][4] = {};
    mfma_nt_core_256(Xh, Wq, M_, C_, m0, n0, As, Bs, acc);

    const int lane = threadIdx.x & 63;
    const int w    = threadIdx.x >> 6;
    const int wm = w >> 2, wn = w & 3;
    const int ln = lane & 15, kq = lane >> 4;

    _Float16* basep[4];
    float     scl[4];
    #pragma unroll
    for (int ni = 0; ni < 4; ++ni) {
        const int d  = n0 + wn * 64 + ni * 16 + ln;
        const int t3 = d / C_;
        const int rr = d - t3 * C_;
        const int h  = rr >> 6;
        const int e  = rr & 63;
        _Float16* tp = (t3 == 0) ? Qh : (t3 == 1) ? Kh : Vh;
        basep[ni] = tp + (size_t)h * N_ * HD_ + e;
        scl[ni]   = (t3 == 0) ? 0.125f : 1.f;
    }
    #pragma unroll
    for (int mi = 0; mi < 8; ++mi) {
        #pragma unroll
        for (int i = 0; i < 4; ++i) {
            const int m = m0 + wm * 128 + mi * 16 + kq * 4 + i;
            if (m >= M_) continue;
            const int b = m / N_;
            const int n = m - b * N_;
            const size_t rowoff = ((size_t)b * H_ * N_ + n) * HD_;
            #pragma unroll
            for (int ni = 0; ni < 4; ++ni)
                basep[ni][rowoff] = (_Float16)(acc[mi][ni][i] * scl[ni]);
        }
    }
}

// ---------------------------------------------------------------------------
// out = O @ w_proj^T + b_proj (128^2 core, fp32 out)
__global__ __launch_bounds__(256) void k_proj_mfma(const _Float16* __restrict__ Oh,
                                                   const _Float16* __restrict__ Wp,
                                                   const float* __restrict__ bias,
                                                   float* __restrict__ out) {
    __shared__ _Float16 As[2 * 4096];
    __shared__ _Float16 Bs[2 * 4096];
    const int work = xcd_swz(blockIdx.y * 6 + blockIdx.x, 6 * 99);
    const int m0 = (work / 6) << 7;
    const int n0 = (work % 6) << 7;
    f32x4 acc[4][4] = {};
    mfma_nt_core_h(Oh, Wp, M_, C_, m0, n0, As, Bs, acc);

    const int lane = threadIdx.x & 63;
    const int wave = threadIdx.x >> 6;
    const int wr = (wave >> 1) << 6, wc = (wave & 1) << 6;
    const int ln = lane & 15, kq = lane >> 4;
    float bv[4];
    #pragma unroll
    for (int nt = 0; nt < 4; ++nt) bv[nt] = bias[n0 + wc + nt * 16 + ln];
    #pragma unroll
    for (int mt = 0; mt < 4; ++mt) {
        #pragma unroll
        for (int i = 0; i < 4; ++i) {
            const int m = m0 + wr + mt * 16 + kq * 4 + i;
            if (m >= M_) continue;
            #pragma unroll
            for (int nt = 0; nt < 4; ++nt)
                out[(size_t)m * C_ + n0 + wc + nt * 16 + ln] = acc[mt][nt][i] + bv[nt];
        }
    }
}

// ---------------------------------------------------------------------------
// Fused attention, ONE block per bh, swapped-QK^T, P entirely in registers.
__global__ __launch_bounds__(256, 3) void k_attn(const _Float16* __restrict__ Qh,
                                                 const _Float16* __restrict__ Kh,
                                                 const _Float16* __restrict__ Vh,
                                                 _Float16* __restrict__ Oh,
                                                 float* __restrict__ P0) {
    __shared__ _Float16 lds[27136];
    _Float16* Ks = lds;            // 208*64 = 13312 halves (swizzled)
    _Float16* Vt = lds + 13312;    // 64*216 = 13824 halves (V^T, key cols)

    const int bh = blockIdx.x;
    const int b = bh / H_, h = bh - b * H_;
    const int tid = threadIdx.x, wave = tid >> 6, lane = tid & 63;
    const int ln = lane & 15, kq = lane >> 4;
    const size_t kvb = (size_t)bh * N_ * HD_;

    // stage K -> Ks[key*64 + 8*(chunk ^ (key&7))]; keys 197..207 zeroed
    for (int idx = tid; idx < 208 * 8; idx += 256) {
        const int key = idx >> 3, c8 = idx & 7;
        half8 v = (key < N_) ? *(const half8*)(Kh + kvb + (size_t)key * HD_ + c8 * 8) : h8zero();
        *(half8*)&Ks[key * 64 + ((c8 ^ (key & 7)) << 3)] = v;
    }
    // stage V transposed -> Vt[d*216 + key]
    for (int idx = tid; idx < 197 * 8; idx += 256) {
        const int key = idx >> 3, c = (idx & 7) << 3;
        half8 v = *(const half8*)(Vh + kvb + (size_t)key * HD_ + c);
        #pragma unroll
        for (int j = 0; j < 8; ++j) Vt[(c + j) * 216 + key] = v[j];
    }
    // zero Vt pad cols 197..215
    for (int idx = tid; idx < 64 * 19; idx += 256) {
        const int d = idx / 19, k = 197 + (idx - d * 19);
        Vt[d * 216 + k] = (_Float16)0;
    }
    __syncthreads();

    const int swz = ln & 7;

    for (int rt = 0; rt < 4; ++rt) {
        if (rt * 64 + wave * 16 >= N_) continue;   // wave-uniform; no barriers

        const int qrow = rt * 64 + wave * 16 + ln;
        const _Float16* Qp = Qh + kvb + (size_t)((qrow < N_) ? qrow : 0) * HD_ + kq * 8;
        half8 qf0 = *(const half8*)Qp;
        half8 qf1 = *(const half8*)(Qp + 32);

        // S^T = K Q^T over 13 key tiles (A=K, B=Q)
        f32x4 acc[13] = {};
        __builtin_amdgcn_s_setprio(1);
        #pragma unroll
        for (int c = 0; c < 13; ++c) {
            const _Float16* kp = &Ks[(c * 16 + ln) * 64];
            half8 kf0 = *(const half8*)(kp + ((kq ^ swz) << 3));
            half8 kf1 = *(const half8*)(kp + (((4 + kq) ^ swz) << 3));
            acc[c] = __builtin_amdgcn_mfma_f32_16x16x32_f16(kf0, qf0, acc[c], 0, 0, 0);
            acc[c] = __builtin_amdgcn_mfma_f32_16x16x32_f16(kf1, qf1, acc[c], 0, 0, 0);
        }
        __builtin_amdgcn_s_setprio(0);

        // softmax: lane (ln,kq) owns q-row ln, keys {c*16+kq*4+r}.
        float m = -1e30f;
        #pragma unroll
        for (int c = 0; c < 12; ++c)
            #pragma unroll
            for (int r = 0; r < 4; ++r) m = fmaxf(m, acc[c][r]);
        #pragma unroll
        for (int r = 0; r < 4; ++r) {
            float x = (kq * 4 + r < 5) ? acc[12][r] : -1e30f;
            acc[12][r] = x;
            m = fmaxf(m, x);
        }
        m = fmaxf(m, __shfl_xor(m, 16));
        m = fmaxf(m, __shfl_xor(m, 32));
        float s = 0.f;
        #pragma unroll
        for (int c = 0; c < 13; ++c)
            #pragma unroll
            for (int r = 0; r < 4; ++r) {
                float e = __expf(acc[c][r] - m);
                acc[c][r] = e;
                s += e;
            }
        s += __shfl_xor(s, 16);
        s += __shfl_xor(s, 32);
        const float inv = 1.f / s;

        // CLS-row probs (q-row 0 lives in lanes ln==0 of wave0, rt0)
        if (rt == 0 && wave == 0 && ln == 0) {
            #pragma unroll
            for (int c = 0; c < 13; ++c)
                #pragma unroll
                for (int r = 0; r < 4; ++r) {
                    const int key = c * 16 + kq * 4 + r;
                    if (key >= 1 && key < N_)
                        P0[(size_t)bh * 196 + key - 1] = acc[c][r] * inv;
                }
        }

        // O = P V via 16x16x16 MFMA: af = P[q=ln][16u+kq*4+j] direct from regs
        f32x4 o4[4] = {};
        __builtin_amdgcn_s_setprio(1);
        #pragma unroll
        for (int u = 0; u < 13; ++u) {
            half4 af;
            af[0] = (_Float16)(acc[u][0] * inv);
            af[1] = (_Float16)(acc[u][1] * inv);
            af[2] = (_Float16)(acc[u][2] * inv);
            af[3] = (_Float16)(acc[u][3] * inv);
            #pragma unroll
            for (int n = 0; n < 4; ++n) {
                half4 bf = *(const half4*)&Vt[(n * 16 + ln) * 216 + u * 16 + kq * 4];
                o4[n] = __builtin_amdgcn_mfma_f32_16x16x16f16(af, bf, o4[n], 0, 0, 0);
            }
        }
        __builtin_amdgcn_s_setprio(0);

        // store O fp16 [B][N][C] (D: row=kq*4+r -> q, col=n*16+ln -> d)
        const int g0 = rt * 64 + wave * 16 + kq * 4;
        #pragma unroll
        for (int r = 0; r < 4; ++r) {
            const int g = g0 + r;
            if (g >= N_) continue;
            _Float16* op = Oh + ((size_t)b * N_ + g) * C_ + h * HD_;
            #pragma unroll
            for (int n = 0; n < 4; ++n) op[n * 16 + ln] = (_Float16)o4[n][r];
        }
    }
}

// ---------------------------------------------------------------------------
// global_attn[b][m] = mean_h P0[b*12+h][m]
__global__ void k_gattn(const float* __restrict__ P0, float* __restrict__ out2) {
    const int idx = blockIdx.x * blockDim.x + threadIdx.x;   // 12544 exact
    const int b = idx / (N_ - 1), m = idx - b * (N_ - 1);
    float s = 0.f;
    #pragma unroll
    for (int h = 0; h < H_; ++h) s += P0[((size_t)(b * H_ + h)) * 196 + m];
    out2[idx] = s * (1.f / H_);
}

// ---------------------------------------------------------------------------
extern "C" void kernel_launch(void* const* d_in, const int* in_sizes, int n_in,
                              void* d_out, int out_size, void* d_ws, size_t ws_size,
                              hipStream_t stream) {
    const float* x      = (const float*)d_in[0];
    const float* w_qkv  = (const float*)d_in[1];
    const float* w_proj = (const float*)d_in[2];
    const float* b_proj = (const float*)d_in[3];
    float* out = (float*)d_out;
    char* ws   = (char*)d_ws;

    if (ws_size < (size_t)WS_BYTES) {
        k_ws_too_small<<<1, 1, 0, stream>>>(out, (float)ws_size);
        return;
    }

    _Float16* Xh  = (_Float16*)(ws + XH_OFF);
    _Float16* Wqh = (_Float16*)(ws + WQH_OFF);
    _Float16* Wph = (_Float16*)(ws + WPH_OFF);
    _Float16* Qh  = (_Float16*)(ws + QH_OFF);
    _Float16* Kh  = (_Float16*)(ws + KH_OFF);
    _Float16* Vh  = (_Float16*)(ws + VH_OFF);
    _Float16* Oh  = (_Float16*)(ws + OH_OFF);
    float*    P0  = (float*)   (ws + P0_OFF);

    k_cvt_all<<<5880, 256, 0, stream>>>(x, w_qkv, w_proj, Xh, Wqh, Wph);

    k_qkv_mfma <<<dim3(450),   512, 0, stream>>>(Xh, Wqh, Qh, Kh, Vh);
    k_attn     <<<dim3(BH_),   256, 0, stream>>>(Qh, Kh, Vh, Oh, P0);
    k_gattn    <<<dim3(49),    256, 0, stream>>>(P0, out + (size_t)M_ * C_);
    k_proj_mfma<<<dim3(6, 99), 256, 0, stream>>>(Oh, Wph, b_proj, out);
}

// Round 10
// 220.104 us; speedup vs baseline: 1.0204x; 1.0204x over previous
//
#include <hip/hip_runtime.h>
#include <math.h>

// Problem constants
#define B_   64
#define N_   197
#define C_   768
#define H_   12
#define HD_  64
#define BH_  (B_ * H_)          // 768
#define M_   (B_ * N_)          // 12608

typedef _Float16 half8 __attribute__((ext_vector_type(8)));
typedef _Float16 half4 __attribute__((ext_vector_type(4)));
typedef float    f32x4 __attribute__((ext_vector_type(4)));

// Workspace byte offsets (all 16B aligned)
#define XH_OFF   0u           // 12608*768 fp16      = 19,365,888 B
#define WQH_OFF  19365888u    // 2304*768 fp16       =  3,538,944 B
#define WPH_OFF  22904832u    // 768*768 fp16        =  1,179,648 B
#define QH_OFF   24084480u    // [bh][197][64] fp16  = 19,365,888 B
#define KH_OFF   43450368u    // [bh][197][64] fp16
#define VH_OFF   62816256u    // [bh][197][64] fp16
#define OH_OFF   82182144u    // [B][N][C] fp16      = 19,365,888 B
#define WS_BYTES 102150144u

__device__ __forceinline__ half8 h8zero() {
    half8 z;
    #pragma unroll
    for (int i = 0; i < 8; ++i) z[i] = (_Float16)0;
    return z;
}

// async 16B global -> LDS (wave-uniform LDS base + lane*16; per-lane global addr)
__device__ __forceinline__ void async16(const _Float16* g, _Float16* l) {
    __builtin_amdgcn_global_load_lds(
        (const __attribute__((address_space(1))) void*)g,
        (__attribute__((address_space(3))) void*)l,
        16, 0, 0);
}

// m204 bijective XCD-chunk swizzle
__device__ __forceinline__ int xcd_swz(int i, int nwg) {
    const int q = nwg >> 3, r = nwg & 7;
    const int xcd = i & 7, j = i >> 3;
    return (xcd < r ? xcd * (q + 1) : r * (q + 1) + (xcd - r) * q) + j;
}

// ---------------------------------------------------------------------------
__global__ void k_ws_too_small(float* out, float ws_bytes) { out[0] = -ws_bytes; }

// ---------------------------------------------------------------------------
// fp32 -> fp16 bulk convert (x, w_qkv, w_proj) + zero out2 (blocks >= 5880).
// out2 must be zeroed each iteration BEFORE k_attn's atomicAdds (stream order).
__global__ __launch_bounds__(256) void k_cvt_all(const float* __restrict__ x,
                                                 const float* __restrict__ wq,
                                                 const float* __restrict__ wp,
                                                 _Float16* __restrict__ Xh,
                                                 _Float16* __restrict__ Wqh,
                                                 _Float16* __restrict__ Wph,
                                                 float* __restrict__ out2) {
    if (blockIdx.x >= 5880) {                      // zero tail: 12544 floats
        const int j = (blockIdx.x - 5880) * 256 + threadIdx.x;
        if (j < 3136) {
            float4 z = {0.f, 0.f, 0.f, 0.f};
            *(float4*)(out2 + (size_t)j * 4) = z;
        }
        return;
    }
    int i = blockIdx.x * blockDim.x + threadIdx.x;
    const float* src;
    _Float16*    dst;
    if (i < 1210368)      { src = x;  dst = Xh; }
    else if (i < 1431552) { src = wq; dst = Wqh; i -= 1210368; }
    else                  { src = wp; dst = Wph; i -= 1431552; }
    float4 f0 = *(const float4*)(src + (size_t)i * 8);
    float4 f1 = *(const float4*)(src + (size_t)i * 8 + 4);
    half8 h;
    h[0]=(_Float16)f0.x; h[1]=(_Float16)f0.y; h[2]=(_Float16)f0.z; h[3]=(_Float16)f0.w;
    h[4]=(_Float16)f1.x; h[5]=(_Float16)f1.y; h[6]=(_Float16)f1.z; h[7]=(_Float16)f1.w;
    *(half8*)(dst + (size_t)i * 8) = h;
}

// ---------------------------------------------------------------------------
// 256x256 NT-GEMM core (qkv): 8 waves, BK=64, 4-phase counted-vmcnt schedule
// (R4 best-measured config). LDS 128 KiB, linear DMA dest, both-sides swizzle.
__device__ __forceinline__ void mfma_nt_core_256(const _Float16* __restrict__ A,
                                                 const _Float16* __restrict__ B,
                                                 int M, int K, int m0, int n0,
                                                 _Float16* As, _Float16* Bs,
                                                 f32x4 (&acc)[8][4]) {
    const int tid  = threadIdx.x;
    const int lane = tid & 63;
    const int w    = tid >> 6;
    const int wm   = w >> 2, wn = w & 3;
    const int ln   = lane & 15, kq = lane >> 4;

    const int srow = tid >> 3;
    const int kcs  = (((tid & 7) ^ (srow & 7)) << 3);
    int ra00 = m0 +       srow; if (ra00 >= M) ra00 = 0;
    int ra01 = m0 +  64 + srow; if (ra01 >= M) ra01 = 0;
    int ra10 = m0 + 128 + srow; if (ra10 >= M) ra10 = 0;
    int ra11 = m0 + 192 + srow; if (ra11 >= M) ra11 = 0;
    const _Float16* A00 = A + (size_t)ra00 * K + kcs;
    const _Float16* A01 = A + (size_t)ra01 * K + kcs;
    const _Float16* A10 = A + (size_t)ra10 * K + kcs;
    const _Float16* A11 = A + (size_t)ra11 * K + kcs;
    const _Float16* B00 = B + (size_t)(n0 +       srow) * K + kcs;
    const _Float16* B01 = B + (size_t)(n0 +  64 + srow) * K + kcs;
    const _Float16* B10 = B + (size_t)(n0 + 128 + srow) * K + kcs;
    const _Float16* B11 = B + (size_t)(n0 + 192 + srow) * K + kcs;
    const int dOff = w << 9;

    const int kx    = (ln & 7) << 3;
    const int aBase = wm * 8192 + ln * 64;
    const int bBase = (wn >> 1) * 8192 + (wn & 1) * 4096 + ln * 64;

    half8 af[4][2], bf[4][2];

    async16(A00, As + dOff);          async16(A01, As + 4096 + dOff);
    async16(A10, As + 8192 + dOff);   async16(A11, As + 12288 + dOff);
    async16(B00, Bs + dOff);          async16(B01, Bs + 4096 + dOff);
    async16(B10, Bs + 8192 + dOff);   async16(B11, Bs + 12288 + dOff);

    const int NT = K >> 6;            // 12
    #pragma unroll 1
    for (int t = 0; t < NT; ++t) {
        const int cur  = (t & 1) << 14;
        const int nb   = 16384 - cur;
        const int koff = (t + 1) << 6;
        const bool pre = (t + 1 < NT);
        const _Float16* Ac = As + cur;
        const _Float16* Bc = Bs + cur;

        if (pre) {
            async16(A00 + koff, As + nb + dOff);
            async16(A01 + koff, As + nb + 4096 + dOff);
            async16(A10 + koff, As + nb + 8192 + dOff);
            async16(A11 + koff, As + nb + 12288 + dOff);
            asm volatile("s_waitcnt vmcnt(4)" ::: "memory");
        } else {
            asm volatile("s_waitcnt vmcnt(0)" ::: "memory");
        }
        __builtin_amdgcn_s_barrier();
        __builtin_amdgcn_sched_barrier(0);
        #pragma unroll
        for (int m4 = 0; m4 < 4; ++m4)
            #pragma unroll
            for (int kk = 0; kk < 2; ++kk)
                af[m4][kk] = *(const half8*)&Ac[aBase + m4 * 1024 + ((kk * 32 + kq * 8) ^ kx)];
        #pragma unroll
        for (int n2 = 0; n2 < 2; ++n2)
            #pragma unroll
            for (int kk = 0; kk < 2; ++kk)
                bf[n2][kk] = *(const half8*)&Bc[bBase + n2 * 1024 + ((kk * 32 + kq * 8) ^ kx)];
        __builtin_amdgcn_s_setprio(1);
        #pragma unroll
        for (int m4 = 0; m4 < 4; ++m4)
            #pragma unroll
            for (int n2 = 0; n2 < 2; ++n2)
                #pragma unroll
                for (int kk = 0; kk < 2; ++kk)
                    acc[m4][n2] = __builtin_amdgcn_mfma_f32_16x16x32_f16(af[m4][kk], bf[n2][kk], acc[m4][n2], 0, 0, 0);
        __builtin_amdgcn_s_setprio(0);
        __builtin_amdgcn_sched_barrier(0);
        __builtin_amdgcn_s_barrier();

        if (pre) {
            async16(B00 + koff, Bs + nb + dOff);
            async16(B01 + koff, Bs + nb + 4096 + dOff);
        }
        #pragma unroll
        for (int n2 = 0; n2 < 2; ++n2)
            #pragma unroll
            for (int kk = 0; kk < 2; ++kk)
                bf[2 + n2][kk] = *(const half8*)&Bc[bBase + (2 + n2) * 1024 + ((kk * 32 + kq * 8) ^ kx)];
        __builtin_amdgcn_s_setprio(1);
        #pragma unroll
        for (int m4 = 0; m4 < 4; ++m4)
            #pragma unroll
            for (int n2 = 0; n2 < 2; ++n2)
                #pragma unroll
                for (int kk = 0; kk < 2; ++kk)
                    acc[m4][2 + n2] = __builtin_amdgcn_mfma_f32_16x16x32_f16(af[m4][kk], bf[2 + n2][kk], acc[m4][2 + n2], 0, 0, 0);
        __builtin_amdgcn_s_setprio(0);
        __builtin_amdgcn_sched_barrier(0);
        __builtin_amdgcn_s_barrier();

        if (pre) {
            async16(B10 + koff, Bs + nb + 8192 + dOff);
            async16(B11 + koff, Bs + nb + 12288 + dOff);
        }
        #pragma unroll
        for (int m4 = 0; m4 < 4; ++m4)
            #pragma unroll
            for (int kk = 0; kk < 2; ++kk)
                af[m4][kk] = *(const half8*)&Ac[aBase + (4 + m4) * 1024 + ((kk * 32 + kq * 8) ^ kx)];
        __builtin_amdgcn_s_setprio(1);
        #pragma unroll
        for (int m4 = 0; m4 < 4; ++m4)
            #pragma unroll
            for (int n2 = 0; n2 < 2; ++n2)
                #pragma unroll
                for (int kk = 0; kk < 2; ++kk)
                    acc[4 + m4][n2] = __builtin_amdgcn_mfma_f32_16x16x32_f16(af[m4][kk], bf[n2][kk], acc[4 + m4][n2], 0, 0, 0);
        __builtin_amdgcn_s_setprio(0);
        __builtin_amdgcn_sched_barrier(0);
        __builtin_amdgcn_s_barrier();

        __builtin_amdgcn_s_setprio(1);
        #pragma unroll
        for (int m4 = 0; m4 < 4; ++m4)
            #pragma unroll
            for (int n2 = 0; n2 < 2; ++n2)
                #pragma unroll
                for (int kk = 0; kk < 2; ++kk)
                    acc[4 + m4][2 + n2] = __builtin_amdgcn_mfma_f32_16x16x32_f16(af[m4][kk], bf[2 + n2][kk], acc[4 + m4][2 + n2], 0, 0, 0);
        __builtin_amdgcn_s_setprio(0);
        asm volatile("s_waitcnt lgkmcnt(0)" ::: "memory");
        __builtin_amdgcn_sched_barrier(0);
        __builtin_amdgcn_s_barrier();
    }
}

// ---------------------------------------------------------------------------
// 128x128 NT-GEMM core (proj): 4 waves, 2-phase dbuf global_load_lds.
__device__ __forceinline__ void mfma_nt_core_h(const _Float16* __restrict__ A,
                                               const _Float16* __restrict__ B,
                                               int M, int K, int m0, int n0,
                                               _Float16* As, _Float16* Bs,
                                               f32x4 (&acc)[4][4]) {
    const int tid  = threadIdx.x;
    const int wave = tid >> 6, lane = tid & 63;
    const int wr   = (wave >> 1) << 6;
    const int wc   = (wave & 1) << 6;
    const int ln   = lane & 15, kq = lane >> 4;

    const int row0 = tid >> 2;
    const int ch0  = (tid & 3) << 3;
    int ar0 = m0 + row0;        if (ar0 >= M) ar0 = 0;
    int ar1 = m0 + 64 + row0;   if (ar1 >= M) ar1 = 0;
    const _Float16* A0 = A + (size_t)ar0 * K + ch0;
    const _Float16* A1 = A + (size_t)ar1 * K + ch0;
    const _Float16* B0 = B + (size_t)(n0 + row0) * K + ch0;
    const _Float16* B1 = B + (size_t)(n0 + 64 + row0) * K + ch0;
    _Float16* AsD = As + (wave << 9);
    _Float16* BsD = Bs + (wave << 9);

    async16(A0, AsD);        async16(A1, AsD + 2048);
    async16(B0, BsD);        async16(B1, BsD + 2048);
    __syncthreads();

    int cur = 0;
    for (int k0 = 0; k0 < K; k0 += 32) {
        const int nxt = cur ^ 1;
        if (k0 + 32 < K) {
            const int nb = nxt << 12;
            async16(A0 + k0 + 32, AsD + nb);
            async16(A1 + k0 + 32, AsD + nb + 2048);
            async16(B0 + k0 + 32, BsD + nb);
            async16(B1 + k0 + 32, BsD + nb + 2048);
        }
        const _Float16* Ac = As + (cur << 12);
        const _Float16* Bc = Bs + (cur << 12);
        half8 af[4], bf[4];
        #pragma unroll
        for (int t = 0; t < 4; ++t) {
            af[t] = *(const half8*)&Ac[(wr + t * 16 + ln) * 32 + kq * 8];
            bf[t] = *(const half8*)&Bc[(wc + t * 16 + ln) * 32 + kq * 8];
        }
        #pragma unroll
        for (int i = 0; i < 4; ++i)
            #pragma unroll
            for (int j = 0; j < 4; ++j)
                acc[i][j] = __builtin_amdgcn_mfma_f32_16x16x32_f16(af[i], bf[j], acc[i][j], 0, 0, 0);
        __syncthreads();
        cur = nxt;
    }
}

// ---------------------------------------------------------------------------
// qkv = x @ w_qkv^T (256^2 core); scatter epilogue -> Qh(x0.125)/Kh/Vh fp16
__global__ __launch_bounds__(512, 2) void k_qkv_mfma(const _Float16* __restrict__ Xh,
                                                     const _Float16* __restrict__ Wq,
                                                     _Float16* __restrict__ Qh,
                                                     _Float16* __restrict__ Kh,
                                                     _Float16* __restrict__ Vh) {
    __shared__ _Float16 As[32768];
    __shared__ _Float16 Bs[32768];
    const int work = xcd_swz(blockIdx.x, 50 * 9);
    const int m0 = (work / 9) << 8;
    const int n0 = (work % 9) << 8;
    f32x4 acc[8][4] = {};
    mfma_nt_core_256(Xh, Wq, M_, C_, m0, n0, As, Bs, acc);

    const int lane = threadIdx.x & 63;
    const int w    = threadIdx.x >> 6;
    const int wm = w >> 2, wn = w & 3;
    const int ln = lane & 15, kq = lane >> 4;

    _Float16* basep[4];
    float     scl[4];
    #pragma unroll
    for (int ni = 0; ni < 4; ++ni) {
        const int d  = n0 + wn * 64 + ni * 16 + ln;
        const int t3 = d / C_;
        const int rr = d - t3 * C_;
        const int h  = rr >> 6;
        const int e  = rr & 63;
        _Float16* tp = (t3 == 0) ? Qh : (t3 == 1) ? Kh : Vh;
        basep[ni] = tp + (size_t)h * N_ * HD_ + e;
        scl[ni]   = (t3 == 0) ? 0.125f : 1.f;
    }
    #pragma unroll
    for (int mi = 0; mi < 8; ++mi) {
        #pragma unroll
        for (int i = 0; i < 4; ++i) {
            const int m = m0 + wm * 128 + mi * 16 + kq * 4 + i;
            if (m >= M_) continue;
            const int b = m / N_;
            const int n = m - b * N_;
            const size_t rowoff = ((size_t)b * H_ * N_ + n) * HD_;
            #pragma unroll
            for (int ni = 0; ni < 4; ++ni)
                basep[ni][rowoff] = (_Float16)(acc[mi][ni][i] * scl[ni]);
        }
    }
}

// ---------------------------------------------------------------------------
// out = O @ w_proj^T + b_proj (128^2 core, fp32 out)
__global__ __launch_bounds__(256) void k_proj_mfma(const _Float16* __restrict__ Oh,
                                                   const _Float16* __restrict__ Wp,
                                                   const float* __restrict__ bias,
                                                   float* __restrict__ out) {
    __shared__ _Float16 As[2 * 4096];
    __shared__ _Float16 Bs[2 * 4096];
    const int work = xcd_swz(blockIdx.y * 6 + blockIdx.x, 6 * 99);
    const int m0 = (work / 6) << 7;
    const int n0 = (work % 6) << 7;
    f32x4 acc[4][4] = {};
    mfma_nt_core_h(Oh, Wp, M_, C_, m0, n0, As, Bs, acc);

    const int lane = threadIdx.x & 63;
    const int wave = threadIdx.x >> 6;
    const int wr = (wave >> 1) << 6, wc = (wave & 1) << 6;
    const int ln = lane & 15, kq = lane >> 4;
    float bv[4];
    #pragma unroll
    for (int nt = 0; nt < 4; ++nt) bv[nt] = bias[n0 + wc + nt * 16 + ln];
    #pragma unroll
    for (int mt = 0; mt < 4; ++mt) {
        #pragma unroll
        for (int i = 0; i < 4; ++i) {
            const int m = m0 + wr + mt * 16 + kq * 4 + i;
            if (m >= M_) continue;
            #pragma unroll
            for (int nt = 0; nt < 4; ++nt)
                out[(size_t)m * C_ + n0 + wc + nt * 16 + ln] = acc[mt][nt][i] + bv[nt];
        }
    }
}

// ---------------------------------------------------------------------------
// Fused attention, ONE block per bh, swapped-QK^T, P in registers.
// K staged via global_load_lds with pre-swizzled source (rows 197..207 garbage,
// masked in softmax). No max-subtraction (|S| <= ~6 -> exp safe in fp32).
// CLS probs atomicAdd directly into out2 (zeroed by k_cvt_all) -> no gattn.
__global__ __launch_bounds__(256, 3) void k_attn(const _Float16* __restrict__ Qh,
                                                 const _Float16* __restrict__ Kh,
                                                 const _Float16* __restrict__ Vh,
                                                 _Float16* __restrict__ Oh,
                                                 float* __restrict__ out2) {
    __shared__ _Float16 lds[27136];
    _Float16* Ks = lds;            // 208*64 = 13312 halves (swizzled)
    _Float16* Vt = lds + 13312;    // 64*216 = 13824 halves (V^T, key cols)

    const int bh = blockIdx.x;
    const int b = bh / H_, h = bh - b * H_;
    const int tid = threadIdx.x, wave = tid >> 6, lane = tid & 63;
    const int ln = lane & 15, kq = lane >> 4;
    const size_t kvb = (size_t)bh * N_ * HD_;

    // stage K via DMA: Ks[row][c8] = K[row][c8 ^ (row&7)] (pre-swizzled source)
    {
        const int row8 = tid >> 3;               // row within 32-row call
        const int c8   = tid & 7;
        #pragma unroll
        for (int l = 0; l < 6; ++l) {
            const int row = l * 32 + row8;
            const _Float16* src = Kh + kvb + (size_t)row * HD_ + ((c8 ^ (row & 7)) << 3);
            async16(src, Ks + l * 2048 + (wave << 9));
        }
        if (wave < 2) {                          // tail rows 192..207
            const int row = 192 + row8;
            const _Float16* src = Kh + kvb + (size_t)row * HD_ + ((c8 ^ (row & 7)) << 3);
            async16(src, Ks + 12288 + (wave << 9));
        }
    }
    // stage V transposed -> Vt[d*216 + key]
    for (int idx = tid; idx < 197 * 8; idx += 256) {
        const int key = idx >> 3, c = (idx & 7) << 3;
        half8 v = *(const half8*)(Vh + kvb + (size_t)key * HD_ + c);
        #pragma unroll
        for (int j = 0; j < 8; ++j) Vt[(c + j) * 216 + key] = v[j];
    }
    // zero Vt pad cols 197..215
    for (int idx = tid; idx < 64 * 19; idx += 256) {
        const int d = idx / 19, k = 197 + (idx - d * 19);
        Vt[d * 216 + k] = (_Float16)0;
    }
    __syncthreads();                             // drains DMA vmcnt + LDS writes

    const int swz = ln & 7;

    for (int rt = 0; rt < 4; ++rt) {
        if (rt * 64 + wave * 16 >= N_) continue;   // wave-uniform; no barriers

        const int qrow = rt * 64 + wave * 16 + ln;
        const _Float16* Qp = Qh + kvb + (size_t)((qrow < N_) ? qrow : 0) * HD_ + kq * 8;
        half8 qf0 = *(const half8*)Qp;
        half8 qf1 = *(const half8*)(Qp + 32);

        // S^T = K Q^T over 13 key tiles (A=K, B=Q)
        f32x4 acc[13] = {};
        __builtin_amdgcn_s_setprio(1);
        #pragma unroll
        for (int c = 0; c < 13; ++c) {
            const _Float16* kp = &Ks[(c * 16 + ln) * 64];
            half8 kf0 = *(const half8*)(kp + ((kq ^ swz) << 3));
            half8 kf1 = *(const half8*)(kp + (((4 + kq) ^ swz) << 3));
            acc[c] = __builtin_amdgcn_mfma_f32_16x16x32_f16(kf0, qf0, acc[c], 0, 0, 0);
            acc[c] = __builtin_amdgcn_mfma_f32_16x16x32_f16(kf1, qf1, acc[c], 0, 0, 0);
        }
        __builtin_amdgcn_s_setprio(0);

        // softmax without max-subtraction (values bounded, fp32-safe).
        // lane (ln,kq) owns q-row ln, keys {c*16+kq*4+r}; mask c=12 keys>=197
        // (incl. garbage-K rows: overwrite with 0, no NaN propagation).
        float s = 0.f;
        #pragma unroll
        for (int c = 0; c < 12; ++c)
            #pragma unroll
            for (int r = 0; r < 4; ++r) {
                float e = __expf(acc[c][r]);
                acc[c][r] = e;
                s += e;
            }
        #pragma unroll
        for (int r = 0; r < 4; ++r) {
            float e = (kq * 4 + r < 5) ? __expf(acc[12][r]) : 0.f;
            acc[12][r] = e;
            s += e;
        }
        s += __shfl_xor(s, 16);
        s += __shfl_xor(s, 32);
        const float inv = 1.f / s;

        // CLS-row probs: mean over heads via atomicAdd into out2[b][key-1]
        if (rt == 0 && wave == 0 && ln == 0) {
            float* o2 = out2 + (size_t)b * 196 - 1;
            #pragma unroll
            for (int c = 0; c < 13; ++c)
                #pragma unroll
                for (int r = 0; r < 4; ++r) {
                    const int key = c * 16 + kq * 4 + r;
                    if (key >= 1 && key < N_)
                        atomicAdd(o2 + key, acc[c][r] * inv * (1.f / H_));
                }
        }

        // O = P V via 16x16x16 MFMA: af = P[q=ln][16u+kq*4+j] direct from regs
        f32x4 o4[4] = {};
        __builtin_amdgcn_s_setprio(1);
        #pragma unroll
        for (int u = 0; u < 13; ++u) {
            half4 af;
            af[0] = (_Float16)(acc[u][0] * inv);
            af[1] = (_Float16)(acc[u][1] * inv);
            af[2] = (_Float16)(acc[u][2] * inv);
            af[3] = (_Float16)(acc[u][3] * inv);
            #pragma unroll
            for (int n = 0; n < 4; ++n) {
                half4 bf = *(const half4*)&Vt[(n * 16 + ln) * 216 + u * 16 + kq * 4];
                o4[n] = __builtin_amdgcn_mfma_f32_16x16x16f16(af, bf, o4[n], 0, 0, 0);
            }
        }
        __builtin_amdgcn_s_setprio(0);

        // store O fp16 [B][N][C] (D: row=kq*4+r -> q, col=n*16+ln -> d)
        const int g0 = rt * 64 + wave * 16 + kq * 4;
        #pragma unroll
        for (int r = 0; r < 4; ++r) {
            const int g = g0 + r;
            if (g >= N_) continue;
            _Float16* op = Oh + ((size_t)b * N_ + g) * C_ + h * HD_;
            #pragma unroll
            for (int n = 0; n < 4; ++n) op[n * 16 + ln] = (_Float16)o4[n][r];
        }
    }
}

// ---------------------------------------------------------------------------
extern "C" void kernel_launch(void* const* d_in, const int* in_sizes, int n_in,
                              void* d_out, int out_size, void* d_ws, size_t ws_size,
                              hipStream_t stream) {
    const float* x      = (const float*)d_in[0];
    const float* w_qkv  = (const float*)d_in[1];
    const float* w_proj = (const float*)d_in[2];
    const float* b_proj = (const float*)d_in[3];
    float* out = (float*)d_out;
    char* ws   = (char*)d_ws;

    if (ws_size < (size_t)WS_BYTES) {
        k_ws_too_small<<<1, 1, 0, stream>>>(out, (float)ws_size);
        return;
    }

    _Float16* Xh  = (_Float16*)(ws + XH_OFF);
    _Float16* Wqh = (_Float16*)(ws + WQH_OFF);
    _Float16* Wph = (_Float16*)(ws + WPH_OFF);
    _Float16* Qh  = (_Float16*)(ws + QH_OFF);
    _Float16* Kh  = (_Float16*)(ws + KH_OFF);
    _Float16* Vh  = (_Float16*)(ws + VH_OFF);
    _Float16* Oh  = (_Float16*)(ws + OH_OFF);
    float*    out2 = out + (size_t)M_ * C_;

    k_cvt_all<<<5893, 256, 0, stream>>>(x, w_qkv, w_proj, Xh, Wqh, Wph, out2);

    k_qkv_mfma <<<dim3(450),   512, 0, stream>>>(Xh, Wqh, Qh, Kh, Vh);
    k_attn     <<<dim3(BH_),   256, 0, stream>>>(Qh, Kh, Vh, Oh, out2);
    k_proj_mfma<<<dim3(6, 99), 256, 0, stream>>>(Oh, Wph, b_proj, out);
}

// Round 11
// 219.523 us; speedup vs baseline: 1.0231x; 1.0026x over previous
//
#include <hip/hip_runtime.h>
#include <math.h>

// Problem constants
#define B_   64
#define N_   197
#define C_   768
#define H_   12
#define HD_  64
#define BH_  (B_ * H_)          // 768
#define M_   (B_ * N_)          // 12608

typedef _Float16 half8 __attribute__((ext_vector_type(8)));
typedef _Float16 half4 __attribute__((ext_vector_type(4)));
typedef float    f32x4 __attribute__((ext_vector_type(4)));

// Workspace byte offsets (all 16B aligned)
#define XH_OFF   0u           // 12608*768 fp16      = 19,365,888 B
#define WQH_OFF  19365888u    // 2304*768 fp16       =  3,538,944 B
#define WPH_OFF  22904832u    // 768*768 fp16        =  1,179,648 B
#define QH_OFF   24084480u    // [bh][197][64] fp16  = 19,365,888 B
#define KH_OFF   43450368u    // [bh][197][64] fp16
#define VH_OFF   62816256u    // [bh][197][64] fp16
#define OH_OFF   82182144u    // [B][N][C] fp16      = 19,365,888 B
#define WS_BYTES 102150144u

__device__ __forceinline__ half8 h8zero() {
    half8 z;
    #pragma unroll
    for (int i = 0; i < 8; ++i) z[i] = (_Float16)0;
    return z;
}

// async 16B global -> LDS (wave-uniform LDS base + lane*16; per-lane global addr)
__device__ __forceinline__ void async16(const _Float16* g, _Float16* l) {
    __builtin_amdgcn_global_load_lds(
        (const __attribute__((address_space(1))) void*)g,
        (__attribute__((address_space(3))) void*)l,
        16, 0, 0);
}

// m204 bijective XCD-chunk swizzle
__device__ __forceinline__ int xcd_swz(int i, int nwg) {
    const int q = nwg >> 3, r = nwg & 7;
    const int xcd = i & 7, j = i >> 3;
    return (xcd < r ? xcd * (q + 1) : r * (q + 1) + (xcd - r) * q) + j;
}

// ---------------------------------------------------------------------------
__global__ void k_ws_too_small(float* out, float ws_bytes) { out[0] = -ws_bytes; }

// ---------------------------------------------------------------------------
// fp32 -> fp16 bulk convert (x, w_qkv, w_proj) + zero out2 (blocks >= 5880).
// out2 must be zeroed each iteration BEFORE k_attn's atomicAdds (stream order).
__global__ __launch_bounds__(256) void k_cvt_all(const float* __restrict__ x,
                                                 const float* __restrict__ wq,
                                                 const float* __restrict__ wp,
                                                 _Float16* __restrict__ Xh,
                                                 _Float16* __restrict__ Wqh,
                                                 _Float16* __restrict__ Wph,
                                                 float* __restrict__ out2) {
    if (blockIdx.x >= 5880) {                      // zero tail: 12544 floats
        const int j = (blockIdx.x - 5880) * 256 + threadIdx.x;
        if (j < 3136) {
            float4 z = {0.f, 0.f, 0.f, 0.f};
            *(float4*)(out2 + (size_t)j * 4) = z;
        }
        return;
    }
    int i = blockIdx.x * blockDim.x + threadIdx.x;
    const float* src;
    _Float16*    dst;
    if (i < 1210368)      { src = x;  dst = Xh; }
    else if (i < 1431552) { src = wq; dst = Wqh; i -= 1210368; }
    else                  { src = wp; dst = Wph; i -= 1431552; }
    float4 f0 = *(const float4*)(src + (size_t)i * 8);
    float4 f1 = *(const float4*)(src + (size_t)i * 8 + 4);
    half8 h;
    h[0]=(_Float16)f0.x; h[1]=(_Float16)f0.y; h[2]=(_Float16)f0.z; h[3]=(_Float16)f0.w;
    h[4]=(_Float16)f1.x; h[5]=(_Float16)f1.y; h[6]=(_Float16)f1.z; h[7]=(_Float16)f1.w;
    *(half8*)(dst + (size_t)i * 8) = h;
}

// ---------------------------------------------------------------------------
// 256x256 NT-GEMM core (qkv): 8 waves (2Mx4N, per-wave 128x64), BK=32,
// 2-buffer dbuf, 64 KiB LDS -> 2 blocks/CU (m114 inter-block overlap; all
// 450 blocks co-resident). Counted vmcnt(4): next tile's loads stay in
// flight across the barrier. Both-sides swizzle: source chunk ^= (row>>1)&3,
// read chunk ^= (ln>>1)&3 (verified 2-way banks = free).
__device__ __forceinline__ void mfma_nt_core_256(const _Float16* __restrict__ A,
                                                 const _Float16* __restrict__ B,
                                                 int M, int K, int m0, int n0,
                                                 _Float16* As, _Float16* Bs,
                                                 f32x4 (&acc)[8][4]) {
    const int tid  = threadIdx.x;
    const int lane = tid & 63;
    const int w    = tid >> 6;
    const int wm   = w >> 2, wn = w & 3;
    const int ln   = lane & 15, kq = lane >> 4;

    // staging: call l covers rows l*128 + (tid>>2); chunk c8 = tid&3.
    const int srow = tid >> 2;                               // 0..127
    const int kcs  = (((tid & 3) ^ ((tid >> 3) & 3)) << 3);  // src col (halves)
    int ra0 = m0 +       srow; if (ra0 >= M) ra0 = 0;        // clamp; garbage
    int ra1 = m0 + 128 + srow; if (ra1 >= M) ra1 = 0;        // dropped in epilogue
    const _Float16* A0 = A + (size_t)ra0 * K + kcs;
    const _Float16* A1 = A + (size_t)ra1 * K + kcs;
    const _Float16* B0 = B + (size_t)(n0 +       srow) * K + kcs;
    const _Float16* B1 = B + (size_t)(n0 + 128 + srow) * K + kcs;
    const int dOff = w << 9;      // wave-uniform dest base (halves) within a call

    // read addressing (A-frag: lane holds A[m=ln][k=kq*8+j])
    const int rdx   = ((kq ^ ((ln >> 1) & 3)) << 3);   // swizzled k-chunk (halves)
    const int aBase = wm * 4096 + ln * 32;
    const int bBase = wn * 2048 + ln * 32;

    // prologue: prime K-tiles 0,1 into bufs 0,1 (4 calls each)
    #pragma unroll
    for (int p = 0; p < 2; ++p) {
        const int koff = p << 5;
        _Float16* dA = As + p * 8192 + dOff;
        _Float16* dB = Bs + p * 8192 + dOff;
        async16(A0 + koff, dA);   async16(A1 + koff, dA + 4096);
        async16(B0 + koff, dB);   async16(B1 + koff, dB + 4096);
    }

    const int NT = K >> 5;        // 24
    #pragma unroll 1
    for (int t = 0; t < NT; ++t) {
        // wait: own 4 loads of tile t done; tile t+1's 4 stay in flight
        if (t < NT - 1) asm volatile("s_waitcnt vmcnt(4)" ::: "memory");
        else            asm volatile("s_waitcnt vmcnt(0)" ::: "memory");
        __builtin_amdgcn_s_barrier();            // all waves' DMA for t landed
        __builtin_amdgcn_sched_barrier(0);

        const int cur = (t & 1) << 13;           // 8192 halves per buffer
        const _Float16* Ac = As + cur;
        const _Float16* Bc = Bs + cur;
        half8 af[8], bf[4];
        #pragma unroll
        for (int m4 = 0; m4 < 8; ++m4)
            af[m4] = *(const half8*)&Ac[aBase + m4 * 512 + rdx];
        #pragma unroll
        for (int n2 = 0; n2 < 4; ++n2)
            bf[n2] = *(const half8*)&Bc[bBase + n2 * 512 + rdx];
        __builtin_amdgcn_s_setprio(1);
        #pragma unroll
        for (int m4 = 0; m4 < 8; ++m4)
            #pragma unroll
            for (int n2 = 0; n2 < 4; ++n2)
                acc[m4][n2] = __builtin_amdgcn_mfma_f32_16x16x32_f16(af[m4], bf[n2], acc[m4][n2], 0, 0, 0);
        __builtin_amdgcn_s_setprio(0);
        asm volatile("s_waitcnt lgkmcnt(0)" ::: "memory");
        __builtin_amdgcn_sched_barrier(0);
        __builtin_amdgcn_s_barrier();            // all reads of buf cur done

        if (t + 2 < NT) {                        // refill cur with tile t+2
            const int koff = (t + 2) << 5;
            _Float16* dA = As + cur + dOff;
            _Float16* dB = Bs + cur + dOff;
            async16(A0 + koff, dA);   async16(A1 + koff, dA + 4096);
            async16(B0 + koff, dB);   async16(B1 + koff, dB + 4096);
        }
    }
}

// ---------------------------------------------------------------------------
// 128x128 NT-GEMM core (proj): 4 waves, 2-phase dbuf global_load_lds.
__device__ __forceinline__ void mfma_nt_core_h(const _Float16* __restrict__ A,
                                               const _Float16* __restrict__ B,
                                               int M, int K, int m0, int n0,
                                               _Float16* As, _Float16* Bs,
                                               f32x4 (&acc)[4][4]) {
    const int tid  = threadIdx.x;
    const int wave = tid >> 6, lane = tid & 63;
    const int wr   = (wave >> 1) << 6;
    const int wc   = (wave & 1) << 6;
    const int ln   = lane & 15, kq = lane >> 4;

    const int row0 = tid >> 2;
    const int ch0  = (tid & 3) << 3;
    int ar0 = m0 + row0;        if (ar0 >= M) ar0 = 0;
    int ar1 = m0 + 64 + row0;   if (ar1 >= M) ar1 = 0;
    const _Float16* A0 = A + (size_t)ar0 * K + ch0;
    const _Float16* A1 = A + (size_t)ar1 * K + ch0;
    const _Float16* B0 = B + (size_t)(n0 + row0) * K + ch0;
    const _Float16* B1 = B + (size_t)(n0 + 64 + row0) * K + ch0;
    _Float16* AsD = As + (wave << 9);
    _Float16* BsD = Bs + (wave << 9);

    async16(A0, AsD);        async16(A1, AsD + 2048);
    async16(B0, BsD);        async16(B1, BsD + 2048);
    __syncthreads();

    int cur = 0;
    for (int k0 = 0; k0 < K; k0 += 32) {
        const int nxt = cur ^ 1;
        if (k0 + 32 < K) {
            const int nb = nxt << 12;
            async16(A0 + k0 + 32, AsD + nb);
            async16(A1 + k0 + 32, AsD + nb + 2048);
            async16(B0 + k0 + 32, BsD + nb);
            async16(B1 + k0 + 32, BsD + nb + 2048);
        }
        const _Float16* Ac = As + (cur << 12);
        const _Float16* Bc = Bs + (cur << 12);
        half8 af[4], bf[4];
        #pragma unroll
        for (int t = 0; t < 4; ++t) {
            af[t] = *(const half8*)&Ac[(wr + t * 16 + ln) * 32 + kq * 8];
            bf[t] = *(const half8*)&Bc[(wc + t * 16 + ln) * 32 + kq * 8];
        }
        #pragma unroll
        for (int i = 0; i < 4; ++i)
            #pragma unroll
            for (int j = 0; j < 4; ++j)
                acc[i][j] = __builtin_amdgcn_mfma_f32_16x16x32_f16(af[i], bf[j], acc[i][j], 0, 0, 0);
        __syncthreads();
        cur = nxt;
    }
}

// ---------------------------------------------------------------------------
// qkv = x @ w_qkv^T (256^2 BK32 2-block/CU core); scatter -> Qh/Kh/Vh fp16
__global__ __launch_bounds__(512, 2) void k_qkv_mfma(const _Float16* __restrict__ Xh,
                                                     const _Float16* __restrict__ Wq,
                                                     _Float16* __restrict__ Qh,
                                                     _Float16* __restrict__ Kh,
                                                     _Float16* __restrict__ Vh) {
    __shared__ _Float16 As[16384];
    __shared__ _Float16 Bs[16384];
    const int work = xcd_swz(blockIdx.x, 50 * 9);
    const int m0 = (work / 9) << 8;
    const int n0 = (work % 9) << 8;
    f32x4 acc[8][4] = {};
    mfma_nt_core_256(Xh, Wq, M_, C_, m0, n0, As, Bs, acc);

    const int lane = threadIdx.x & 63;
    const int w    = threadIdx.x >> 6;
    const int wm = w >> 2, wn = w & 3;
    const int ln = lane & 15, kq = lane >> 4;

    _Float16* basep[4];
    float     scl[4];
    #pragma unroll
    for (int ni = 0; ni < 4; ++ni) {
        const int d  = n0 + wn * 64 + ni * 16 + ln;
        const int t3 = d / C_;
        const int rr = d - t3 * C_;
        const int h  = rr >> 6;
        const int e  = rr & 63;
        _Float16* tp = (t3 == 0) ? Qh : (t3 == 1) ? Kh : Vh;
        basep[ni] = tp + (size_t)h * N_ * HD_ + e;
        scl[ni]   = (t3 == 0) ? 0.125f : 1.f;
    }
    #pragma unroll
    for (int mi = 0; mi < 8; ++mi) {
        #pragma unroll
        for (int i = 0; i < 4; ++i) {
            const int m = m0 + wm * 128 + mi * 16 + kq * 4 + i;
            if (m >= M_) continue;
            const int b = m / N_;
            const int n = m - b * N_;
            const size_t rowoff = ((size_t)b * H_ * N_ + n) * HD_;
            #pragma unroll
            for (int ni = 0; ni < 4; ++ni)
                basep[ni][rowoff] = (_Float16)(acc[mi][ni][i] * scl[ni]);
        }
    }
}

// ---------------------------------------------------------------------------
// out = O @ w_proj^T + b_proj (128^2 core, fp32 out)
__global__ __launch_bounds__(256) void k_proj_mfma(const _Float16* __restrict__ Oh,
                                                   const _Float16* __restrict__ Wp,
                                                   const float* __restrict__ bias,
                                                   float* __restrict__ out) {
    __shared__ _Float16 As[2 * 4096];
    __shared__ _Float16 Bs[2 * 4096];
    const int work = xcd_swz(blockIdx.y * 6 + blockIdx.x, 6 * 99);
    const int m0 = (work / 6) << 7;
    const int n0 = (work % 6) << 7;
    f32x4 acc[4][4] = {};
    mfma_nt_core_h(Oh, Wp, M_, C_, m0, n0, As, Bs, acc);

    const int lane = threadIdx.x & 63;
    const int wave = threadIdx.x >> 6;
    const int wr = (wave >> 1) << 6, wc = (wave & 1) << 6;
    const int ln = lane & 15, kq = lane >> 4;
    float bv[4];
    #pragma unroll
    for (int nt = 0; nt < 4; ++nt) bv[nt] = bias[n0 + wc + nt * 16 + ln];
    #pragma unroll
    for (int mt = 0; mt < 4; ++mt) {
        #pragma unroll
        for (int i = 0; i < 4; ++i) {
            const int m = m0 + wr + mt * 16 + kq * 4 + i;
            if (m >= M_) continue;
            #pragma unroll
            for (int nt = 0; nt < 4; ++nt)
                out[(size_t)m * C_ + n0 + wc + nt * 16 + ln] = acc[mt][nt][i] + bv[nt];
        }
    }
}

// ---------------------------------------------------------------------------
// Fused attention, ONE block per bh, swapped-QK^T, P in registers.
// K staged via global_load_lds with pre-swizzled source (rows 197..207 garbage,
// masked in softmax). No max-subtraction (|S| <= ~6 -> exp safe in fp32).
// CLS probs atomicAdd directly into out2 (zeroed by k_cvt_all) -> no gattn.
__global__ __launch_bounds__(256, 3) void k_attn(const _Float16* __restrict__ Qh,
                                                 const _Float16* __restrict__ Kh,
                                                 const _Float16* __restrict__ Vh,
                                                 _Float16* __restrict__ Oh,
                                                 float* __restrict__ out2) {
    __shared__ _Float16 lds[27136];
    _Float16* Ks = lds;            // 208*64 = 13312 halves (swizzled)
    _Float16* Vt = lds + 13312;    // 64*216 = 13824 halves (V^T, key cols)

    const int bh = blockIdx.x;
    const int b = bh / H_, h = bh - b * H_;
    const int tid = threadIdx.x, wave = tid >> 6, lane = tid & 63;
    const int ln = lane & 15, kq = lane >> 4;
    const size_t kvb = (size_t)bh * N_ * HD_;

    // stage K via DMA: Ks[row][c8] = K[row][c8 ^ (row&7)] (pre-swizzled source)
    {
        const int row8 = tid >> 3;               // row within 32-row call
        const int c8   = tid & 7;
        #pragma unroll
        for (int l = 0; l < 6; ++l) {
            const int row = l * 32 + row8;
            const _Float16* src = Kh + kvb + (size_t)row * HD_ + ((c8 ^ (row & 7)) << 3);
            async16(src, Ks + l * 2048 + (wave << 9));
        }
        if (wave < 2) {                          // tail rows 192..207
            const int row = 192 + row8;
            const _Float16* src = Kh + kvb + (size_t)row * HD_ + ((c8 ^ (row & 7)) << 3);
            async16(src, Ks + 12288 + (wave << 9));
        }
    }
    // stage V transposed -> Vt[d*216 + key]
    for (int idx = tid; idx < 197 * 8; idx += 256) {
        const int key = idx >> 3, c = (idx & 7) << 3;
        half8 v = *(const half8*)(Vh + kvb + (size_t)key * HD_ + c);
        #pragma unroll
        for (int j = 0; j < 8; ++j) Vt[(c + j) * 216 + key] = v[j];
    }
    // zero Vt pad cols 197..215
    for (int idx = tid; idx < 64 * 19; idx += 256) {
        const int d = idx / 19, k = 197 + (idx - d * 19);
        Vt[d * 216 + k] = (_Float16)0;
    }
    __syncthreads();                             // drains DMA vmcnt + LDS writes

    const int swz = ln & 7;

    for (int rt = 0; rt < 4; ++rt) {
        if (rt * 64 + wave * 16 >= N_) continue;   // wave-uniform; no barriers

        const int qrow = rt * 64 + wave * 16 + ln;
        const _Float16* Qp = Qh + kvb + (size_t)((qrow < N_) ? qrow : 0) * HD_ + kq * 8;
        half8 qf0 = *(const half8*)Qp;
        half8 qf1 = *(const half8*)(Qp + 32);

        // S^T = K Q^T over 13 key tiles (A=K, B=Q)
        f32x4 acc[13] = {};
        __builtin_amdgcn_s_setprio(1);
        #pragma unroll
        for (int c = 0; c < 13; ++c) {
            const _Float16* kp = &Ks[(c * 16 + ln) * 64];
            half8 kf0 = *(const half8*)(kp + ((kq ^ swz) << 3));
            half8 kf1 = *(const half8*)(kp + (((4 + kq) ^ swz) << 3));
            acc[c] = __builtin_amdgcn_mfma_f32_16x16x32_f16(kf0, qf0, acc[c], 0, 0, 0);
            acc[c] = __builtin_amdgcn_mfma_f32_16x16x32_f16(kf1, qf1, acc[c], 0, 0, 0);
        }
        __builtin_amdgcn_s_setprio(0);

        // softmax without max-subtraction (values bounded, fp32-safe).
        // lane (ln,kq) owns q-row ln, keys {c*16+kq*4+r}; mask c=12 keys>=197
        // (incl. garbage-K rows: overwrite with 0, no NaN propagation).
        float s = 0.f;
        #pragma unroll
        for (int c = 0; c < 12; ++c)
            #pragma unroll
            for (int r = 0; r < 4; ++r) {
                float e = __expf(acc[c][r]);
                acc[c][r] = e;
                s += e;
            }
        #pragma unroll
        for (int r = 0; r < 4; ++r) {
            float e = (kq * 4 + r < 5) ? __expf(acc[12][r]) : 0.f;
            acc[12][r] = e;
            s += e;
        }
        s += __shfl_xor(s, 16);
        s += __shfl_xor(s, 32);
        const float inv = 1.f / s;

        // CLS-row probs: mean over heads via atomicAdd into out2[b][key-1]
        if (rt == 0 && wave == 0 && ln == 0) {
            float* o2 = out2 + (size_t)b * 196 - 1;
            #pragma unroll
            for (int c = 0; c < 13; ++c)
                #pragma unroll
                for (int r = 0; r < 4; ++r) {
                    const int key = c * 16 + kq * 4 + r;
                    if (key >= 1 && key < N_)
                        atomicAdd(o2 + key, acc[c][r] * inv * (1.f / H_));
                }
        }

        // O = P V via 16x16x16 MFMA: af = P[q=ln][16u+kq*4+j] direct from regs
        f32x4 o4[4] = {};
        __builtin_amdgcn_s_setprio(1);
        #pragma unroll
        for (int u = 0; u < 13; ++u) {
            half4 af;
            af[0] = (_Float16)(acc[u][0] * inv);
            af[1] = (_Float16)(acc[u][1] * inv);
            af[2] = (_Float16)(acc[u][2] * inv);
            af[3] = (_Float16)(acc[u][3] * inv);
            #pragma unroll
            for (int n = 0; n < 4; ++n) {
                half4 bf = *(const half4*)&Vt[(n * 16 + ln) * 216 + u * 16 + kq * 4];
                o4[n] = __builtin_amdgcn_mfma_f32_16x16x16f16(af, bf, o4[n], 0, 0, 0);
            }
        }
        __builtin_amdgcn_s_setprio(0);

        // store O fp16 [B][N][C] (D: row=kq*4+r -> q, col=n*16+ln -> d)
        const int g0 = rt * 64 + wave * 16 + kq * 4;
        #pragma unroll
        for (int r = 0; r < 4; ++r) {
            const int g = g0 + r;
            if (g >= N_) continue;
            _Float16* op = Oh + ((size_t)b * N_ + g) * C_ + h * HD_;
            #pragma unroll
            for (int n = 0; n < 4; ++n) op[n * 16 + ln] = (_Float16)o4[n][r];
        }
    }
}

// ---------------------------------------------------------------------------
extern "C" void kernel_launch(void* const* d_in, const int* in_sizes, int n_in,
                              void* d_out, int out_size, void* d_ws, size_t ws_size,
                              hipStream_t stream) {
    const float* x      = (const float*)d_in[0];
    const float* w_qkv  = (const float*)d_in[1];
    const float* w_proj = (const float*)d_in[2];
    const float* b_proj = (const float*)d_in[3];
    float* out = (float*)d_out;
    char* ws   = (char*)d_ws;

    if (ws_size < (size_t)WS_BYTES) {
        k_ws_too_small<<<1, 1, 0, stream>>>(out, (float)ws_size);
        return;
    }

    _Float16* Xh  = (_Float16*)(ws + XH_OFF);
    _Float16* Wqh = (_Float16*)(ws + WQH_OFF);
    _Float16* Wph = (_Float16*)(ws + WPH_OFF);
    _Float16* Qh  = (_Float16*)(ws + QH_OFF);
    _Float16* Kh  = (_Float16*)(ws + KH_OFF);
    _Float16* Vh  = (_Float16*)(ws + VH_OFF);
    _Float16* Oh  = (_Float16*)(ws + OH_OFF);
    float*    out2 = out + (size_t)M_ * C_;

    k_cvt_all<<<5893, 256, 0, stream>>>(x, w_qkv, w_proj, Xh, Wqh, Wph, out2);

    k_qkv_mfma <<<dim3(450),   512, 0, stream>>>(Xh, Wqh, Qh, Kh, Vh);
    k_attn     <<<dim3(BH_),   256, 0, stream>>>(Qh, Kh, Vh, Oh, out2);
    k_proj_mfma<<<dim3(6, 99), 256, 0, stream>>>(Oh, Wph, b_proj, out);
}